// Round 1
// baseline (192.055 us; speedup 1.0000x reference)
//
#include <hip/hip_runtime.h>

// ShiftImgPreprocessor: out[b,t,c,i,j] = img[b,t,c, clamp(i+sy-4,0,95), clamp(j+sx-4,0,95)] / 255 - 0.5
// Pure memory-bound clamped gather. One thread per float4 of output.

#define PAD 4
#define NB  256   // batch
#define TT  4
#define CC  3
#define HH  96
#define WW  96
#define W4  (WW / 4)            // 24 float4 per row
#define ROWS_PER_B (TT * CC * HH)       // 1152
#define V4_PER_B (ROWS_PER_B * W4)      // 27648 float4 per batch
#define BLOCK 256

__global__ __launch_bounds__(BLOCK) void ShiftImgPreprocessor_36679020708143_kernel(
    const float* __restrict__ img,
    const int*   __restrict__ shift,
    float*       __restrict__ out)
{
    const int b = blockIdx.y;
    const int v = blockIdx.x * BLOCK + threadIdx.x;   // [0, V4_PER_B)

    const int j4 = v % W4;           // which float4 in the row
    const int r  = v / W4;           // row index within batch: [0, T*C*H)
    const int i  = r % HH;           // output row
    const int tc = r / HH;           // fused (t,c) plane index

    // wave-uniform per block -> scalar loads
    const int dx = shift[2 * b + 0] - PAD;   // in [-4, 4]
    const int dy = shift[2 * b + 1] - PAD;

    const int yy = min(max(i + dy, 0), HH - 1);

    const size_t plane = ((size_t)b * (TT * CC) + tc) * (size_t)(HH * WW);
    const float* __restrict__ src = img + plane + (size_t)yy * WW;

    const int j = j4 * 4;
    const int x0 = min(max(j + 0 + dx, 0), WW - 1);
    const int x1 = min(max(j + 1 + dx, 0), WW - 1);
    const int x2 = min(max(j + 2 + dx, 0), WW - 1);
    const int x3 = min(max(j + 3 + dx, 0), WW - 1);

    const float k = 1.0f / 255.0f;
    float4 o;
    o.x = src[x0] * k - 0.5f;
    o.y = src[x1] * k - 0.5f;
    o.z = src[x2] * k - 0.5f;
    o.w = src[x3] * k - 0.5f;

    float4* outv = (float4*)(out + plane + (size_t)i * WW + j);
    *outv = o;
}

extern "C" void kernel_launch(void* const* d_in, const int* in_sizes, int n_in,
                              void* d_out, int out_size, void* d_ws, size_t ws_size,
                              hipStream_t stream) {
    const float* img   = (const float*)d_in[0];
    const int*   shift = (const int*)d_in[1];
    float*       out   = (float*)d_out;

    dim3 grid(V4_PER_B / BLOCK, NB);   // (108, 256)
    ShiftImgPreprocessor_36679020708143_kernel<<<grid, BLOCK, 0, stream>>>(img, shift, out);
}

// Round 3
// 191.269 us; speedup vs baseline: 1.0041x; 1.0041x over previous
//
#include <hip/hip_runtime.h>

// ShiftImgPreprocessor: out[b,t,c,i,j] = img[b,t,c, clamp(i+sy-4,0,95), clamp(j+sx-4,0,95)] / 255 - 0.5
// Memory-bound clamped gather. dx,dy are block-uniform (one b per blockIdx.y),
// so each output row is a 4B-misaligned contiguous copy of a source row plus
// <=4 replicated edge pixels. Interior lanes: two aligned coalesced dwordx4
// loads + scalar-branch select on phase r = dx&3. Edge lanes (j4==0 / j4==23,
// 2 of 24): scalar clamped gather.

#define PAD 4
#define NB  256   // batch
#define TT  4
#define CC  3
#define HH  96
#define WW  96
#define W4  (WW / 4)                    // 24 float4 per row
#define ROWS_PER_B (TT * CC * HH)       // 1152
#define V4_PER_B (ROWS_PER_B * W4)      // 27648 float4 per batch
#define BLOCK 256

typedef float vfloat4 __attribute__((ext_vector_type(4)));  // native clang vector: OK for nontemporal builtins

__global__ __launch_bounds__(BLOCK) void ShiftImgPreprocessor_36679020708143_kernel(
    const float* __restrict__ img,
    const int*   __restrict__ shift,
    float*       __restrict__ out)
{
    const int b = blockIdx.y;
    const int v = blockIdx.x * BLOCK + threadIdx.x;   // [0, V4_PER_B)

    const int j4 = v % W4;           // which float4 in the row
    const int r_ = v / W4;           // row index within batch: [0, T*C*H)
    const int i  = r_ % HH;          // output row
    const int tc = r_ / HH;          // fused (t,c) plane index

    // block-uniform -> SGPR loads
    const int dx = shift[2 * b + 0] - PAD;   // in [-4, 4]
    const int dy = shift[2 * b + 1] - PAD;

    const int yy = min(max(i + dy, 0), HH - 1);

    const size_t plane = ((size_t)b * (TT * CC) + tc) * (size_t)(HH * WW);
    const float* __restrict__ srcrow = img + plane + (size_t)yy * WW;

    const int j = j4 * 4;
    const float k = 1.0f / 255.0f;
    vfloat4 o;

    if (j4 == 0 || j4 == W4 - 1) {
        // edge float4: may need horizontal clamping -> scalar clamped gather
        const int x0 = min(max(j + 0 + dx, 0), WW - 1);
        const int x1 = min(max(j + 1 + dx, 0), WW - 1);
        const int x2 = min(max(j + 2 + dx, 0), WW - 1);
        const int x3 = min(max(j + 3 + dx, 0), WW - 1);
        o = (vfloat4){srcrow[x0], srcrow[x1], srcrow[x2], srcrow[x3]};
    } else {
        // interior: s = j+dx in [0,92]; source floats s..s+3 live in vecs a4, a4+1
        const int s  = j + dx;
        const int a4 = s >> 2;                 // consecutive lanes -> consecutive vecs
        const int r  = dx & 3;                 // SGPR-uniform phase -> scalar branch
        const vfloat4* __restrict__ sv = (const vfloat4*)srcrow;
        const vfloat4 V0 = sv[a4];
        const vfloat4 V1 = sv[min(a4 + 1, W4 - 1)];   // unused when r==0; clamp avoids OOB
        switch (r) {
            case 0:  o = V0; break;
            case 1:  o = (vfloat4){V0.y, V0.z, V0.w, V1.x}; break;
            case 2:  o = (vfloat4){V0.z, V0.w, V1.x, V1.y}; break;
            default: o = (vfloat4){V0.w, V1.x, V1.y, V1.z}; break;
        }
    }

    o = o * k - 0.5f;

    vfloat4* outv = (vfloat4*)(out + plane + (size_t)i * WW + j);
    __builtin_nontemporal_store(o, outv);
}

extern "C" void kernel_launch(void* const* d_in, const int* in_sizes, int n_in,
                              void* d_out, int out_size, void* d_ws, size_t ws_size,
                              hipStream_t stream) {
    const float* img   = (const float*)d_in[0];
    const int*   shift = (const int*)d_in[1];
    float*       out   = (float*)d_out;

    dim3 grid(V4_PER_B / BLOCK, NB);   // (108, 256)
    ShiftImgPreprocessor_36679020708143_kernel<<<grid, BLOCK, 0, stream>>>(img, shift, out);
}